// Round 1
// baseline (1026.443 us; speedup 1.0000x reference)
//
#include <hip/hip_runtime.h>
#include <cmath>

#define NMUL 32
#define IN_DIM 128
#define MSG_DIM 128

__global__ __launch_bounds__(256)
void tp_scatter_kernel(const float* __restrict__ x,
                       const float* __restrict__ edge_attr,
                       const float* __restrict__ edge_weight,
                       const int* __restrict__ edge_src,
                       const int* __restrict__ edge_dst,
                       float* __restrict__ out)
{
    const float INV_SQRT3 = 0.5773502691896258f;
    const float PATH_NORM = 0.125f;            // 1/sqrt(2*32)

    const int e   = blockIdx.x;
    const int tid = threadIdx.x;
    const int u   = tid >> 3;   // 0..31 : reduction index
    const int wq  = tid & 7;    // 0..7  : 4 output columns each (w = wq*4..wq*4+3)

    __shared__ float xs0[NMUL];
    __shared__ float x1s[NMUL * 3];
    __shared__ float sS[NMUL];
    __shared__ float red[256 * 17];            // stride 17 -> conflict-free

    const int src = edge_src[e];
    const int dst = edge_dst[e];
    const float4 ea = ((const float4*)edge_attr)[e];
    const float e0  = ea.x;
    const float e1x = ea.y, e1y = ea.z, e1z = ea.w;

    // stage x[src] row: first 32 = x0, next 96 = x1 (u-major, 3 per u)
    if (tid < IN_DIM) {
        float v = x[(size_t)src * IN_DIM + tid];
        if (tid < NMUL) xs0[tid] = v;
        else            x1s[tid - NMUL] = v;
    }
    __syncthreads();
    if (tid < NMUL) {
        sS[tid] = x1s[tid*3 + 0]*e1x + x1s[tid*3 + 1]*e1y + x1s[tid*3 + 2]*e1z;
    }
    __syncthreads();

    // per-thread scalars for its fixed u
    const float x0u = xs0[u];
    const float su  = sS[u];
    const float x10 = x1s[u*3 + 0];
    const float x11 = x1s[u*3 + 1];
    const float x12 = x1s[u*3 + 2];

    const float c000 = e0 * x0u;              // feeds w000 into out0
    const float c110 = INV_SQRT3 * su;        // feeds w110 into out0
    const float b0 = x0u * e1x, b1 = x0u * e1y, b2 = x0u * e1z;  // w011 -> out1[:,k]
    const float d0 = x10 * e0,  d1 = x11 * e0,  d2 = x12 * e0;   // w101 -> out1[:,k]

    // weights: 4 matrices of 1024 floats, [u][w] with w contiguous.
    // thread reads float4 at (u*32 + wq*4) = tid*4 floats -> fully coalesced.
    const float4* W4 = (const float4*)edge_weight + (size_t)e * 1024;
    const float4 w000 = W4[0*256 + tid];
    const float4 w011 = W4[1*256 + tid];
    const float4 w101 = W4[2*256 + tid];
    const float4 w110 = W4[3*256 + tid];

    float* r = red + tid * 17;
    // slots 0..3  : out0 partial (4 cols)
    r[0]  = w000.x*c000 + w110.x*c110;
    r[1]  = w000.y*c000 + w110.y*c110;
    r[2]  = w000.z*c000 + w110.z*c110;
    r[3]  = w000.w*c000 + w110.w*c110;
    // slots 4+k*4+c : out1 partial for k, col c
    r[4]  = w011.x*b0 + w101.x*d0;
    r[5]  = w011.y*b0 + w101.y*d0;
    r[6]  = w011.z*b0 + w101.z*d0;
    r[7]  = w011.w*b0 + w101.w*d0;
    r[8]  = w011.x*b1 + w101.x*d1;
    r[9]  = w011.y*b1 + w101.y*d1;
    r[10] = w011.z*b1 + w101.z*d1;
    r[11] = w011.w*b1 + w101.w*d1;
    r[12] = w011.x*b2 + w101.x*d2;
    r[13] = w011.y*b2 + w101.y*d2;
    r[14] = w011.z*b2 + w101.z*d2;
    r[15] = w011.w*b2 + w101.w*d2;
    __syncthreads();

    // threads 0..127: one message element each; reduce over the 32 u-partials
    if (tid < MSG_DIM) {
        int wqo, slot;
        float scale;
        if (tid < 32) {
            wqo  = tid >> 2;
            slot = tid & 3;
            scale = PATH_NORM;
        } else {
            int j = tid - 32;       // out1 flat index = w*3 + k
            int w = j / 3;
            int k = j - 3 * w;
            wqo  = w >> 2;
            slot = 4 + k*4 + (w & 3);
            scale = PATH_NORM * INV_SQRT3;
        }
        float sacc = 0.0f;
        #pragma unroll
        for (int uu = 0; uu < 32; ++uu)
            sacc += red[(uu*8 + wqo) * 17 + slot];
        float v = sacc * scale;
        if (!isfinite(v)) v = 0.0f;   // nan_to_num(nan/±inf -> 0)
        atomicAdd(out + (size_t)dst * MSG_DIM + tid, v);
    }
}

extern "C" void kernel_launch(void* const* d_in, const int* in_sizes, int n_in,
                              void* d_out, int out_size, void* d_ws, size_t ws_size,
                              hipStream_t stream) {
    const float* x           = (const float*)d_in[0];
    const float* edge_attr   = (const float*)d_in[1];
    const float* edge_weight = (const float*)d_in[2];
    const int*   edge_src    = (const int*)d_in[3];
    const int*   edge_dst    = (const int*)d_in[4];
    float*       out         = (float*)d_out;

    const int E = in_sizes[3];

    hipMemsetAsync(d_out, 0, (size_t)out_size * sizeof(float), stream);
    tp_scatter_kernel<<<E, 256, 0, stream>>>(x, edge_attr, edge_weight,
                                             edge_src, edge_dst, out);
}